// Round 1
// baseline (476.866 us; speedup 1.0000x reference)
//
#include <hip/hip_runtime.h>

// Problem constants
#define NBANDS 8
#define BS 32            // box size
#define MTF 41           // MTF kernel size
#define IMG 552          // input image dim
#define CONV 512         // after 41x41 VALID conv
#define QOUT 481         // after 32x32 VALID box conv
#define NIMG 32          // 4 batch * 8 bands
#define NN 1024.0f       // N = BS*BS

// ---------------- Kernel A: 41x41 depthwise conv ----------------
// Tile: 64 (x) x 32 (y) outputs per block, 256 threads.
// Thread (tx in 0..63, tyw in 0..3) computes 8 consecutive y-outputs at column tx.
#define TW 64
#define TH 32
#define IPW (TW + MTF - 1)   // 104
#define IPH (TH + MTF - 1)   // 72
#define WPITCH 44            // padded transposed-weight row pitch (float4-aligned)

__global__ __launch_bounds__(256) void mtf_conv_kernel(
    const float* __restrict__ in,    // [NIMG][552][552]
    const float* __restrict__ wt,    // [8][1][41][41]
    float* __restrict__ out)         // [NIMG][512][512]
{
    __shared__ __align__(16) float s_in[IPH * IPW];      // 29952 B
    __shared__ __align__(16) float s_wt[MTF * WPITCH];   // 7216 B (transposed: [kx][ky])

    const int bid = blockIdx.x;
    const int img = bid >> 7;        // 128 tiles per image
    const int t   = bid & 127;
    const int ty_tile = t >> 3;      // 0..15
    const int tx_tile = t & 7;       // 0..7
    const int band = img & 7;

    const float* imgp = in + (size_t)img * IMG * IMG
                           + (size_t)(ty_tile * TH) * IMG + tx_tile * TW;
    const float* wp = wt + band * MTF * MTF;

    // stage weights transposed: s_wt[kx*WPITCH + ky] = w[ky][kx]
    for (int i = threadIdx.x; i < MTF * MTF; i += 256) {
        int ky = i / MTF, kx = i - ky * MTF;
        s_wt[kx * WPITCH + ky] = wp[i];
    }
    // stage input tile: 72 rows x 26 float4 (104 floats), all in-bounds by construction
    for (int i = threadIdx.x; i < IPH * 26; i += 256) {
        int r = i / 26, c4 = i - r * 26;
        float4 v = *(const float4*)(imgp + (size_t)r * IMG + c4 * 4);
        *(float4*)(s_in + r * IPW + c4 * 4) = v;
    }
    __syncthreads();

    const int tx  = threadIdx.x & 63;
    const int tyw = threadIdx.x >> 6;
    const int ybase = tyw * 8;

    float acc[8];
#pragma unroll
    for (int k = 0; k < 8; ++k) acc[k] = 0.f;

#pragma unroll 1
    for (int kx = 0; kx < MTF; ++kx) {
        const float* col  = s_in + ybase * IPW + tx + kx;
        const float* wcol = s_wt + kx * WPITCH;
        // rolling 8-row register window: v[(ky+j)&7] = row ybase+ky+j
        float v[8];
#pragma unroll
        for (int i = 0; i < 8; ++i) v[i] = col[i * IPW];
#pragma unroll
        for (int kg = 0; kg < 10; ++kg) {
            const float4 w4 = *(const float4*)(wcol + (kg << 2));
            const float wv[4] = {w4.x, w4.y, w4.z, w4.w};
#pragma unroll
            for (int s = 0; s < 4; ++s) {
                const int ky = (kg << 2) + s;
#pragma unroll
                for (int k = 0; k < 8; ++k) acc[k] += wv[s] * v[(ky + k) & 7];
                v[ky & 7] = col[(ky + 8) * IPW];   // ky<=39 here, row <= ybase+47 <= 71
            }
        }
        {   // tail ky = 40 (no ring refresh)
            const float w = wcol[40];
#pragma unroll
            for (int k = 0; k < 8; ++k) acc[k] += w * v[(40 + k) & 7];
        }
    }

    float* op = out + (size_t)img * CONV * CONV
                    + (size_t)(ty_tile * TH + ybase) * CONV + tx_tile * TW + tx;
#pragma unroll
    for (int k = 0; k < 8; ++k) op[(size_t)k * CONV] = acc[k];
}

// ---------------- Kernel B: fused box-sums + Q-map + reduction ----------------
// One block per (image, row-strip). 512 threads; thread x keeps 5 vertical
// running sums over 32 rows at column x; per output row a horizontal prefix
// scan gives the 32-wide window sums; Q computed and accumulated.
#define TR 31    // output rows per strip; 481 = 15*31 + 16 -> 16 strips

__global__ __launch_bounds__(512) void box_q_kernel(
    const float* __restrict__ o,     // [NIMG][512][512]
    const float* __restrict__ lab,   // [NIMG][512][512]
    double* __restrict__ acc)
{
    __shared__ float s_pref[5][512];
    __shared__ float s_wsum[5][8];
    __shared__ float s_red[8];

    const int bid   = blockIdx.x;
    const int img   = bid >> 4;
    const int strip = bid & 15;
    const int r0    = strip * TR;
    const int nrows = min(TR, QOUT - r0);

    const float* op = o   + (size_t)img * CONV * CONV;
    const float* lp = lab + (size_t)img * CONV * CONV;

    const int x    = threadIdx.x;
    const int lane = x & 63;
    const int wv   = x >> 6;

    float s[5] = {0.f, 0.f, 0.f, 0.f, 0.f};
    for (int r = r0; r < r0 + BS; ++r) {
        float ov = op[(size_t)r * CONV + x];
        float lv = lp[(size_t)r * CONV + x];
        s[0] += ov; s[1] += lv; s[2] += ov * ov; s[3] += lv * lv; s[4] += ov * lv;
    }

    float qacc = 0.f;
    for (int i = 0; i < nrows; ++i) {
        float p[5];
#pragma unroll
        for (int c = 0; c < 5; ++c) {
            float v = s[c];
#pragma unroll
            for (int d = 1; d < 64; d <<= 1) {
                float tt = __shfl_up(v, d, 64);
                if (lane >= d) v += tt;
            }
            p[c] = v;
            if (lane == 63) s_wsum[c][wv] = v;
        }
        __syncthreads();
#pragma unroll
        for (int c = 0; c < 5; ++c) {
            float off = 0.f;
            for (int w = 0; w < wv; ++w) off += s_wsum[c][w];
            s_pref[c][x] = p[c] + off;
        }
        __syncthreads();

        if (x < QOUT) {
            float A[5];
#pragma unroll
            for (int c = 0; c < 5; ++c)
                A[c] = s_pref[c][x + 31] - (x ? s_pref[c][x - 1] : 0.f);
            float mul = A[0] * A[1];
            float sq  = A[0] * A[0] + A[1] * A[1];
            float num = 4.f * (NN * A[4] - mul) * mul;
            float dt  = NN * (A[2] + A[3]) - sq;
            float den = dt * sq;
            float q = 1.f;
            if (dt == 0.f && sq != 0.f) q = 2.f * mul / sq;
            if (den != 0.f) q = num / den;
            qacc += q;
        }

        if (i + 1 < nrows) {
            int radd = r0 + i + BS;
            int rsub = r0 + i;
            float oa = op[(size_t)radd * CONV + x], la = lp[(size_t)radd * CONV + x];
            float ob = op[(size_t)rsub * CONV + x], lb = lp[(size_t)rsub * CONV + x];
            s[0] += oa - ob;
            s[1] += la - lb;
            s[2] += oa * oa - ob * ob;
            s[3] += la * la - lb * lb;
            s[4] += oa * la - ob * lb;
        }
        __syncthreads();   // protect s_wsum/s_pref reuse next iteration
    }

    // block reduction of qacc
    float v = qacc;
#pragma unroll
    for (int d = 32; d; d >>= 1) v += __shfl_down(v, d, 64);
    if (lane == 0) s_red[wv] = v;
    __syncthreads();
    if (x == 0) {
        float t = 0.f;
#pragma unroll
        for (int w = 0; w < 8; ++w) t += s_red[w];
        atomicAdd(acc, (double)t);
    }
}

__global__ void finalize_kernel(const double* __restrict__ acc, float* __restrict__ out)
{
    out[0] = 1.0f - (float)(acc[0] / 7403552.0);   // 4*8*481*481
}

extern "C" void kernel_launch(void* const* d_in, const int* in_sizes, int n_in,
                              void* d_out, int out_size, void* d_ws, size_t ws_size,
                              hipStream_t stream)
{
    const float* outputs = (const float*)d_in[0];   // [4,8,552,552]
    const float* labels  = (const float*)d_in[1];   // [4,8,512,512]
    const float* mtf     = (const float*)d_in[2];   // [8,1,41,41]

    double* acc  = (double*)d_ws;                          // 8 B accumulator
    float* o_buf = (float*)((char*)d_ws + 256);            // 33.6 MB conv output

    hipMemsetAsync(d_ws, 0, 16, stream);

    // Kernel A: 32 images * 128 tiles
    mtf_conv_kernel<<<NIMG * 128, 256, 0, stream>>>(outputs, mtf, o_buf);

    // Kernel B: 32 images * 16 strips
    box_q_kernel<<<NIMG * 16, 512, 0, stream>>>(o_buf, labels, acc);

    finalize_kernel<<<1, 1, 0, stream>>>(acc, (float*)d_out);
}

// Round 2
// 194.931 us; speedup vs baseline: 2.4463x; 2.4463x over previous
//
#include <hip/hip_runtime.h>

// Problem constants
#define NBANDS 8
#define BS 32
#define MTF 41
#define IMG 552
#define CONV 512
#define QOUT 481
#define NIMG 32
#define NN 1024.0f

// Transposed fp16 input T: [NIMG][TX][TY], zero-padded
#define TX 560
#define TY 576

typedef _Float16 half8 __attribute__((ext_vector_type(8)));
typedef float float4v __attribute__((ext_vector_type(4)));

// ---------- prep 1: transpose + fp16 convert ----------
// T[img][x][y] = fp16(in[img][y][x]), zero outside 552x552
__global__ __launch_bounds__(256) void prep_transpose(
    const float* __restrict__ in, _Float16* __restrict__ T)
{
    __shared__ _Float16 s[64][72];
    int bid = blockIdx.x;
    int img = bid / 81;            // 9x9 tiles of 64
    int t = bid % 81;
    int ty = t / 9, tx2 = t % 9;
    int y0 = ty * 64, x0 = tx2 * 64;
    const float* ip = in + (size_t)img * IMG * IMG;

    for (int k = 0; k < 16; ++k) {
        int i = k * 256 + threadIdx.x;
        int r = i >> 6, c = i & 63;
        int y = y0 + r, x = x0 + c;
        float v = (y < IMG && x < IMG) ? ip[(size_t)y * IMG + x] : 0.f;
        s[c][r] = (_Float16)v;
    }
    __syncthreads();
    _Float16* Tp = T + (size_t)img * TX * TY;
    for (int k = 0; k < 2; ++k) {
        int i = k * 256 + threadIdx.x;  // 512 = 64 xi * 8 g
        int xi = i >> 3, g = i & 7;
        int x = x0 + xi;
        if (x < TX) {
            half8 v = *(const half8*)&s[xi][g * 8];
            *(half8*)&Tp[(size_t)x * TY + y0 + g * 8] = v;
        }
    }
}

// ---------- prep 2: Toeplitz A-table in MFMA A-frag layout ----------
// Atab[band][kx][s][lane][j] fp16 ; A[row][k] = w[k-row][kx], row=lane&15,
// k = s*32 + (lane>>4)*8 + j
__global__ __launch_bounds__(128) void prep_atab(
    const float* __restrict__ w, _Float16* __restrict__ A)
{
    int band = blockIdx.x / MTF;
    int kx = blockIdx.x % MTF;
    int s = threadIdx.x >> 6, lane = threadIdx.x & 63;
    int row = lane & 15;
    int kb = s * 32 + ((lane >> 4) << 3);
    const float* wp = w + band * MTF * MTF;
    half8 v;
#pragma unroll
    for (int j = 0; j < 8; ++j) {
        int ky = kb + j - row;
        v[j] = (ky >= 0 && ky < MTF) ? (_Float16)wp[ky * MTF + kx] : (_Float16)0.f;
    }
    *(half8*)&A[(((size_t)(band * MTF + kx) * 2 + s) << 9) + lane * 8] = v;
}

// ---------- Kernel A: MFMA depthwise 41x41 conv ----------
// Block: 64x64 output tile, 4 waves (each wave: 16 y-rows x 64 x-cols).
// LDS: transposed input slab sT[x 0..111][y 0..127] fp16, XOR-swizzled.
__global__ __launch_bounds__(256) void conv_mfma(
    const _Float16* __restrict__ T, const _Float16* __restrict__ Atab,
    float* __restrict__ out)
{
    __shared__ __align__(16) _Float16 sT[112 * 128];   // 28672 B
    int bid = blockIdx.x;
    int img = bid >> 6;
    int t = bid & 63;
    int y0 = (t >> 3) << 6;
    int x0 = (t & 7) << 6;
    int band = img & 7;

    const _Float16* Tp = T + (size_t)img * TX * TY;
    {
        int g = threadIdx.x & 15;       // y-group (8 halfs)
        int xb = threadIdx.x >> 4;      // x within pass
        for (int it = 0; it < 7; ++it) {
            int x = xb + it * 16;       // 0..111
            half8 v = *(const half8*)&Tp[(size_t)(x0 + x) * TY + y0 + g * 8];
            int sw = x & 7;
            *(half8*)((char*)sT + ((x << 8) + ((g ^ sw) << 4))) = v;
        }
    }
    __syncthreads();

    int lane = threadIdx.x & 63;
    int wid  = threadIdx.x >> 6;
    int n = lane & 15, g4 = lane >> 4;
    int gyb = (wid << 1) + g4;          // y-group base (s=0): y = 16*wid + 8*g4
    const _Float16* Ap = Atab + (((size_t)band * MTF) << 10) + lane * 8;

    float4v acc[4];
#pragma unroll
    for (int i = 0; i < 4; ++i) acc[i] = (float4v){0.f, 0.f, 0.f, 0.f};

    for (int kx = 0; kx < MTF; ++kx) {
        half8 A0 = *(const half8*)(Ap);
        half8 A1 = *(const half8*)(Ap + 512);
        Ap += 1024;
        int xb0 = n + kx;
#pragma unroll
        for (int t2 = 0; t2 < 4; ++t2) {
            int x = xb0 + (t2 << 4);    // <= 103 < 112
            int sw = x & 7;
            half8 B0 = *(const half8*)((const char*)sT +
                        ((x << 8) + ((gyb ^ sw) << 4)));
            half8 B1 = *(const half8*)((const char*)sT +
                        ((x << 8) + (((gyb + 4) ^ sw) << 4)));
            acc[t2] = __builtin_amdgcn_mfma_f32_16x16x32_f16(A0, B0, acc[t2], 0, 0, 0);
            acc[t2] = __builtin_amdgcn_mfma_f32_16x16x32_f16(A1, B1, acc[t2], 0, 0, 0);
        }
    }

    float* op = out + (size_t)img * CONV * CONV;
    int row0 = y0 + (wid << 4) + (g4 << 2);   // C: col = lane&15, row = g4*4+r
    int col0 = x0 + n;
#pragma unroll
    for (int t2 = 0; t2 < 4; ++t2) {
#pragma unroll
        for (int r = 0; r < 4; ++r)
            op[(size_t)(row0 + r) * CONV + col0 + (t2 << 4)] = acc[t2][r];
    }
}

// ---------------- Kernel B: fused box-sums + Q-map + reduction ----------------
#define TR 31    // output rows per strip; 481 = 15*31 + 16 -> 16 strips

__global__ __launch_bounds__(512) void box_q_kernel(
    const float* __restrict__ o,     // [NIMG][512][512]
    const float* __restrict__ lab,   // [NIMG][512][512]
    double* __restrict__ acc)
{
    __shared__ float s_pref[5][512];
    __shared__ float s_wsum[5][8];
    __shared__ float s_red[8];

    const int bid   = blockIdx.x;
    const int img   = bid >> 4;
    const int strip = bid & 15;
    const int r0    = strip * TR;
    const int nrows = min(TR, QOUT - r0);

    const float* op = o   + (size_t)img * CONV * CONV;
    const float* lp = lab + (size_t)img * CONV * CONV;

    const int x    = threadIdx.x;
    const int lane = x & 63;
    const int wv   = x >> 6;

    float s[5] = {0.f, 0.f, 0.f, 0.f, 0.f};
    for (int r = r0; r < r0 + BS; ++r) {
        float ov = op[(size_t)r * CONV + x];
        float lv = lp[(size_t)r * CONV + x];
        s[0] += ov; s[1] += lv; s[2] += ov * ov; s[3] += lv * lv; s[4] += ov * lv;
    }

    float qacc = 0.f;
    for (int i = 0; i < nrows; ++i) {
        float p[5];
#pragma unroll
        for (int c = 0; c < 5; ++c) {
            float v = s[c];
#pragma unroll
            for (int d = 1; d < 64; d <<= 1) {
                float tt = __shfl_up(v, d, 64);
                if (lane >= d) v += tt;
            }
            p[c] = v;
            if (lane == 63) s_wsum[c][wv] = v;
        }
        __syncthreads();
#pragma unroll
        for (int c = 0; c < 5; ++c) {
            float off = 0.f;
            for (int w = 0; w < wv; ++w) off += s_wsum[c][w];
            s_pref[c][x] = p[c] + off;
        }
        __syncthreads();

        if (x < QOUT) {
            float A[5];
#pragma unroll
            for (int c = 0; c < 5; ++c)
                A[c] = s_pref[c][x + 31] - (x ? s_pref[c][x - 1] : 0.f);
            float mul = A[0] * A[1];
            float sq  = A[0] * A[0] + A[1] * A[1];
            float num = 4.f * (NN * A[4] - mul) * mul;
            float dt  = NN * (A[2] + A[3]) - sq;
            float den = dt * sq;
            float q = 1.f;
            if (dt == 0.f && sq != 0.f) q = 2.f * mul / sq;
            if (den != 0.f) q = num / den;
            qacc += q;
        }

        if (i + 1 < nrows) {
            int radd = r0 + i + BS;
            int rsub = r0 + i;
            float oa = op[(size_t)radd * CONV + x], la = lp[(size_t)radd * CONV + x];
            float ob = op[(size_t)rsub * CONV + x], lb = lp[(size_t)rsub * CONV + x];
            s[0] += oa - ob;
            s[1] += la - lb;
            s[2] += oa * oa - ob * ob;
            s[3] += la * la - lb * lb;
            s[4] += oa * la - ob * lb;
        }
        __syncthreads();
    }

    float v = qacc;
#pragma unroll
    for (int d = 32; d; d >>= 1) v += __shfl_down(v, d, 64);
    if (lane == 0) s_red[wv] = v;
    __syncthreads();
    if (x == 0) {
        float tsum = 0.f;
#pragma unroll
        for (int w = 0; w < 8; ++w) tsum += s_red[w];
        atomicAdd(acc, (double)tsum);
    }
}

__global__ void finalize_kernel(const double* __restrict__ acc, float* __restrict__ out)
{
    out[0] = 1.0f - (float)(acc[0] / 7403552.0);   // 4*8*481*481
}

extern "C" void kernel_launch(void* const* d_in, const int* in_sizes, int n_in,
                              void* d_out, int out_size, void* d_ws, size_t ws_size,
                              hipStream_t stream)
{
    const float* outputs = (const float*)d_in[0];   // [4,8,552,552]
    const float* labels  = (const float*)d_in[1];   // [4,8,512,512]
    const float* mtf     = (const float*)d_in[2];   // [8,1,41,41]

    double*    acc   = (double*)d_ws;                                   // @0
    float*     o_buf = (float*)((char*)d_ws + 4096);                    // 33.55 MB
    _Float16*  T     = (_Float16*)((char*)d_ws + 4096 + 33554432);      // 20.64 MB
    _Float16*  Atab  = (_Float16*)((char*)d_ws + 4096 + 33554432 + 20643840); // 672 KB

    hipMemsetAsync(d_ws, 0, 16, stream);

    prep_transpose<<<NIMG * 81, 256, 0, stream>>>(outputs, T);
    prep_atab<<<NBANDS * MTF, 128, 0, stream>>>(mtf, Atab);
    conv_mfma<<<NIMG * 64, 256, 0, stream>>>(T, Atab, o_buf);
    box_q_kernel<<<NIMG * 16, 512, 0, stream>>>(o_buf, labels, acc);
    finalize_kernel<<<1, 1, 0, stream>>>(acc, (float*)d_out);
}

// Round 3
// 139.260 us; speedup vs baseline: 3.4243x; 1.3998x over previous
//
#include <hip/hip_runtime.h>

// Problem constants
#define NBANDS 8
#define BS 32
#define MTF 41
#define IMG 552
#define CONV 512
#define QOUT 481
#define NIMG 32
#define NN 1024.0f

// Transposed fp16 input T: [NIMG][TX][TY], zero-padded
#define TX 560
#define TY 576

typedef _Float16 half8 __attribute__((ext_vector_type(8)));
typedef float float4v __attribute__((ext_vector_type(4)));

// ---------- prep 1: transpose + fp16 convert ----------
__global__ __launch_bounds__(256) void prep_transpose(
    const float* __restrict__ in, _Float16* __restrict__ T)
{
    __shared__ _Float16 s[64][72];
    int bid = blockIdx.x;
    int img = bid / 81;            // 9x9 tiles of 64
    int t = bid % 81;
    int ty = t / 9, tx2 = t % 9;
    int y0 = ty * 64, x0 = tx2 * 64;
    const float* ip = in + (size_t)img * IMG * IMG;

    for (int k = 0; k < 16; ++k) {
        int i = k * 256 + threadIdx.x;
        int r = i >> 6, c = i & 63;
        int y = y0 + r, x = x0 + c;
        float v = (y < IMG && x < IMG) ? ip[(size_t)y * IMG + x] : 0.f;
        s[c][r] = (_Float16)v;
    }
    __syncthreads();
    _Float16* Tp = T + (size_t)img * TX * TY;
    for (int k = 0; k < 2; ++k) {
        int i = k * 256 + threadIdx.x;  // 512 = 64 xi * 8 g
        int xi = i >> 3, g = i & 7;
        int x = x0 + xi;
        if (x < TX) {
            half8 v = *(const half8*)&s[xi][g * 8];
            *(half8*)&Tp[(size_t)x * TY + y0 + g * 8] = v;
        }
    }
}

// ---------- prep 2: Toeplitz A-table in MFMA A-frag layout ----------
__global__ __launch_bounds__(128) void prep_atab(
    const float* __restrict__ w, _Float16* __restrict__ A)
{
    int band = blockIdx.x / MTF;
    int kx = blockIdx.x % MTF;
    int s = threadIdx.x >> 6, lane = threadIdx.x & 63;
    int row = lane & 15;
    int kb = s * 32 + ((lane >> 4) << 3);
    const float* wp = w + band * MTF * MTF;
    half8 v;
#pragma unroll
    for (int j = 0; j < 8; ++j) {
        int ky = kb + j - row;
        v[j] = (ky >= 0 && ky < MTF) ? (_Float16)wp[ky * MTF + kx] : (_Float16)0.f;
    }
    *(half8*)&A[(((size_t)(band * MTF + kx) * 2 + s) << 9) + lane * 8] = v;
}

// ---------- Kernel A: MFMA depthwise 41x41 conv ----------
__global__ __launch_bounds__(256) void conv_mfma(
    const _Float16* __restrict__ T, const _Float16* __restrict__ Atab,
    float* __restrict__ out)
{
    __shared__ __align__(16) _Float16 sT[112 * 128];   // 28672 B
    int bid = blockIdx.x;
    int img = bid >> 6;
    int t = bid & 63;
    int y0 = (t >> 3) << 6;
    int x0 = (t & 7) << 6;
    int band = img & 7;

    const _Float16* Tp = T + (size_t)img * TX * TY;
    {
        int g = threadIdx.x & 15;
        int xb = threadIdx.x >> 4;
        for (int it = 0; it < 7; ++it) {
            int x = xb + it * 16;
            half8 v = *(const half8*)&Tp[(size_t)(x0 + x) * TY + y0 + g * 8];
            int sw = x & 7;
            *(half8*)((char*)sT + ((x << 8) + ((g ^ sw) << 4))) = v;
        }
    }
    __syncthreads();

    int lane = threadIdx.x & 63;
    int wid  = threadIdx.x >> 6;
    int n = lane & 15, g4 = lane >> 4;
    int gyb = (wid << 1) + g4;
    const _Float16* Ap = Atab + (((size_t)band * MTF) << 10) + lane * 8;

    float4v acc[4];
#pragma unroll
    for (int i = 0; i < 4; ++i) acc[i] = (float4v){0.f, 0.f, 0.f, 0.f};

    for (int kx = 0; kx < MTF; ++kx) {
        half8 A0 = *(const half8*)(Ap);
        half8 A1 = *(const half8*)(Ap + 512);
        Ap += 1024;
        int xb0 = n + kx;
#pragma unroll
        for (int t2 = 0; t2 < 4; ++t2) {
            int x = xb0 + (t2 << 4);
            int sw = x & 7;
            half8 B0 = *(const half8*)((const char*)sT +
                        ((x << 8) + ((gyb ^ sw) << 4)));
            half8 B1 = *(const half8*)((const char*)sT +
                        ((x << 8) + (((gyb + 4) ^ sw) << 4)));
            acc[t2] = __builtin_amdgcn_mfma_f32_16x16x32_f16(A0, B0, acc[t2], 0, 0, 0);
            acc[t2] = __builtin_amdgcn_mfma_f32_16x16x32_f16(A1, B1, acc[t2], 0, 0, 0);
        }
    }

    float* op = out + (size_t)img * CONV * CONV;
    int row0 = y0 + (wid << 4) + (g4 << 2);
    int col0 = x0 + n;
#pragma unroll
    for (int t2 = 0; t2 < 4; ++t2) {
#pragma unroll
        for (int r = 0; r < 4; ++r)
            op[(size_t)(row0 + r) * CONV + col0 + (t2 << 4)] = acc[t2][r];
    }
}

// ---------------- Kernel B: wave-streaming box-sums + Q ----------------
// Each wave: 64 input columns (c0..c0+63), 32 output columns (c0..c0+31).
// Vertical 32-row sliding colsums in registers; horizontal 32-window via
// 6-op DPP wave scan + one bpermute gather. No LDS, no barriers.
#define H_STRIP 64   // output rows per strip; 8 strips (7*64 + 33)

template<int C, int RM, int BM, bool BC>
__device__ __forceinline__ float dppadd(float v) {
    int t = __builtin_amdgcn_update_dpp(0, __builtin_bit_cast(int, v), C, RM, BM, BC);
    return v + __builtin_bit_cast(float, t);
}

__device__ __forceinline__ float wave_iscan(float v) {
    v = dppadd<0x111, 0xf, 0xf, true >(v);   // row_shr:1
    v = dppadd<0x112, 0xf, 0xf, true >(v);   // row_shr:2
    v = dppadd<0x114, 0xf, 0xf, true >(v);   // row_shr:4
    v = dppadd<0x118, 0xf, 0xf, true >(v);   // row_shr:8
    v = dppadd<0x142, 0xa, 0xf, false>(v);   // row_bcast:15 -> rows 1,3
    v = dppadd<0x143, 0xc, 0xf, false>(v);   // row_bcast:31 -> rows 2,3
    return v;
}

// window sum over lanes [l, l+31] (valid for l <= 32)
__device__ __forceinline__ float win32(float s, int lane) {
    float P = wave_iscan(s);
    float Pg = __shfl(P, lane + 31, 64);
    return Pg - P + s;
}

__global__ __launch_bounds__(512) void box_q_wave(
    const float* __restrict__ o,     // [NIMG][512][512]
    const float* __restrict__ lab,   // [NIMG][512][512]
    double* __restrict__ acc)        // acc[NIMG]
{
    int bid   = blockIdx.x;
    int img   = bid >> 4;
    int strip = (bid >> 1) & 7;
    int xblk  = bid & 1;
    int wid   = threadIdx.x >> 6;
    int lane  = threadIdx.x & 63;

    int c0 = xblk * 256 + wid * 32;
    int c  = c0 + lane;
    bool cvalid = c < CONV;
    int r0 = strip * H_STRIP;
    int nrows = min(H_STRIP, QOUT - r0);

    const float* op = o   + (size_t)img * CONV * CONV + c;
    const float* lp = lab + (size_t)img * CONV * CONV + c;

    float s0 = 0.f, s1 = 0.f, s2 = 0.f, s3 = 0.f, s4 = 0.f;
#pragma unroll 4
    for (int r = r0; r < r0 + BS; ++r) {
        float ov = cvalid ? op[(size_t)r * CONV] : 0.f;
        float lv = cvalid ? lp[(size_t)r * CONV] : 0.f;
        s0 += ov; s1 += lv; s2 += ov * ov; s3 += lv * lv; s4 += ov * lv;
    }

    int x = c0 + lane;
    bool xvalid = (lane < 32) && (x < QOUT);
    float qacc = 0.f;

    for (int i = 0;; ++i) {
        // prefetch next-row slide data early (overlaps the scan chain)
        float oa = 0.f, la = 0.f, ob = 0.f, lb = 0.f;
        bool more = (i + 1 < nrows);
        if (more && cvalid) {
            int radd = r0 + i + BS, rsub = r0 + i;
            oa = op[(size_t)radd * CONV]; la = lp[(size_t)radd * CONV];
            ob = op[(size_t)rsub * CONV]; lb = lp[(size_t)rsub * CONV];
        }

        float A0 = win32(s0, lane);
        float A1 = win32(s1, lane);
        float A2 = win32(s2, lane);
        float A3 = win32(s3, lane);
        float A4 = win32(s4, lane);

        if (xvalid) {
            float mul = A0 * A1;
            float sq  = A0 * A0 + A1 * A1;
            float num = 4.f * (NN * A4 - mul) * mul;
            float dt  = NN * (A2 + A3) - sq;
            float den = dt * sq;
            float q = 1.f;
            if (dt == 0.f && sq != 0.f) q = 2.f * mul / sq;
            if (den != 0.f) q = num / den;
            qacc += q;
        }

        if (!more) break;
        s0 += oa - ob;
        s1 += la - lb;
        s2 += oa * oa - ob * ob;
        s3 += la * la - lb * lb;
        s4 += oa * la - ob * lb;
    }

    // reduce lanes 0..31 (lanes >=32 hold 0) and one atomic per wave
    qacc += __shfl_down(qacc, 16, 64);
    qacc += __shfl_down(qacc, 8, 64);
    qacc += __shfl_down(qacc, 4, 64);
    qacc += __shfl_down(qacc, 2, 64);
    qacc += __shfl_down(qacc, 1, 64);
    if (lane == 0) atomicAdd(&acc[img], (double)qacc);
}

__global__ void finalize_kernel(const double* __restrict__ acc, float* __restrict__ out)
{
    double t = 0.0;
    for (int i = 0; i < NIMG; ++i) t += acc[i];
    out[0] = 1.0f - (float)(t / 7403552.0);   // 4*8*481*481
}

extern "C" void kernel_launch(void* const* d_in, const int* in_sizes, int n_in,
                              void* d_out, int out_size, void* d_ws, size_t ws_size,
                              hipStream_t stream)
{
    const float* outputs = (const float*)d_in[0];   // [4,8,552,552]
    const float* labels  = (const float*)d_in[1];   // [4,8,512,512]
    const float* mtf     = (const float*)d_in[2];   // [8,1,41,41]

    double*    acc   = (double*)d_ws;                                   // 32 doubles
    float*     o_buf = (float*)((char*)d_ws + 4096);                    // 33.55 MB
    _Float16*  T     = (_Float16*)((char*)d_ws + 4096 + 33554432);      // 20.64 MB
    _Float16*  Atab  = (_Float16*)((char*)d_ws + 4096 + 33554432 + 20643840); // 672 KB

    hipMemsetAsync(d_ws, 0, 256, stream);

    prep_transpose<<<NIMG * 81, 256, 0, stream>>>(outputs, T);
    prep_atab<<<NBANDS * MTF, 128, 0, stream>>>(mtf, Atab);
    conv_mfma<<<NIMG * 64, 256, 0, stream>>>(T, Atab, o_buf);
    box_q_wave<<<NIMG * 16, 512, 0, stream>>>(o_buf, labels, acc);
    finalize_kernel<<<1, 1, 0, stream>>>(acc, (float*)d_out);
}